// Round 9
// baseline (15.948 us; speedup 1.0000x reference)
//
#include <hip/hip_runtime.h>

// Problem constants (fixed by setup_inputs)
#define BB 16
#define SS 1024
#define NW 8
#define QB 64
#define NH 4
#define TP 67   // Tpart lane-dim stride (odd => spread banks on column reads)

// Raw moments T[j][i] = sum_k (mf*u)^j (mf*v)^i over keys, j+i <= 9 (55, triangle
// index m = s(s+1)/2 + j with s=j+i). Weights use Taylor(exp, deg 8): j+i<=8.
__global__ __launch_bounds__(256)
void mhaq_one(const float* __restrict__ x, const int* __restrict__ mask,
              const float* __restrict__ theta, const float* __restrict__ wout,
              float* __restrict__ out)
{
    __shared__ float2 P[NH][SS];        // (u*mf, v*mf) per head/key: 32 KB
    __shared__ float  Tpart[NH][55][TP];// per-lane moment partials: ~59 KB
    __shared__ float  Qf[QB][NW];       // unmasked q features (this chunk)
    __shared__ float  O[QB][NW];        // attention outputs pre-projection
    __shared__ float  W[64];
    __shared__ float  Traw[NH][55];
    __shared__ float  Ts[NH][9][12], Ta[NH][9][12], Tb[NH][9][12];
    __shared__ int    CMcnt;            // masked-key count

    const int tid = threadIdx.x;
    const int b   = blockIdx.x >> 4;
    const int qc  = blockIdx.x & 15;

    if (tid == 0) CMcnt = 0;

    float th[NW];
#pragma unroll
    for (int e = 0; e < NW; ++e) th[e] = theta[e];

    // ---------- P1: features for all 1024 rows of batch b (4 rows/thread) ----------
    int localMasked = 0;
#pragma unroll
    for (int c = 0; c < 4; ++c) {
        const int row = tid + 256 * c;
        const float* xr = x + ((size_t)b * SS + row) * NW;
        const float4 r0 = *reinterpret_cast<const float4*>(xr);
        const float4 r1 = *reinterpret_cast<const float4*>(xr + 4);
        float g[NW];
        g[0] = __cosf(r0.x + th[0]); g[1] = __cosf(r0.y + th[1]);
        g[2] = __cosf(r0.z + th[2]); g[3] = __cosf(r0.w + th[3]);
        g[4] = __cosf(r1.x + th[4]); g[5] = __cosf(r1.y + th[5]);
        g[6] = __cosf(r1.z + th[6]); g[7] = __cosf(r1.w + th[7]);
        float h[NW];
        h[1] = g[0] * g[1]; h[2] = h[1] * g[2]; h[3] = h[2] * g[3];
        h[4] = h[3] * g[4]; h[5] = h[4] * g[5]; h[6] = h[5] * g[6];
        h[7] = h[6] * g[7];
        h[0] = (g[1] * g[2]) * (g[3] * g[4]) * ((g[5] * g[6]) * g[7]);
        const float mf = (mask[b * SS + row] != 0) ? 1.0f : 0.0f;
        localMasked += (mf == 0.0f) ? 1 : 0;
#pragma unroll
        for (int hd = 0; hd < NH; ++hd)
            P[hd][row] = make_float2(h[2 * hd] * mf, h[2 * hd + 1] * mf);
        const int r = row - qc * QB;
        if ((unsigned)r < (unsigned)QB) {
            *reinterpret_cast<float4*>(&Qf[r][0]) = make_float4(h[0], h[1], h[2], h[3]);
            *reinterpret_cast<float4*>(&Qf[r][4]) = make_float4(h[4], h[5], h[6], h[7]);
        }
    }
    if (localMasked) atomicAdd(&CMcnt, localMasked);
    if (tid < 64) W[tid] = wout[tid];
    __syncthreads();

    // ---------- P2: moment partials; wave = head, lane = 16-key slice ----------
    {
        const int hd = tid >> 6, lane = tid & 63;
        float acc[55];
#pragma unroll
        for (int m = 1; m < 55; ++m) acc[m] = 0.0f;
#pragma unroll 4
        for (int c = 0; c < 16; ++c) {
            const float2 uv = P[hd][c * 64 + lane];
            float muj[10], mvi[10];
            muj[0] = 1.0f; muj[1] = uv.x;
            mvi[0] = 1.0f; mvi[1] = uv.y;
#pragma unroll
            for (int j = 2; j <= 9; ++j) { muj[j] = muj[j - 1] * uv.x; mvi[j] = mvi[j - 1] * uv.y; }
#pragma unroll
            for (int s = 1; s <= 9; ++s)
#pragma unroll
                for (int j = 0; j <= s; ++j)
                    acc[s * (s + 1) / 2 + j] =
                        __builtin_fmaf(muj[j], mvi[s - j], acc[s * (s + 1) / 2 + j]);
        }
        // spill per-lane partials (consecutive-lane addresses -> conflict-free)
#pragma unroll
        for (int m = 1; m < 55; ++m) Tpart[hd][m][lane] = acc[m];
    }
    __syncthreads();

    // ---------- P2b: column-sum the 64 lane-partials; thread = (head, moment) ----------
    if (tid < NH * 55) {
        const int hh = tid / 55, m = tid % 55;
        if (m == 0) {
            Traw[hh][0] = (float)(SS - CMcnt);  // moment (0,0) = unmasked count
        } else {
            const float* col = &Tpart[hh][m][0];
            float t0 = 0.f, t1 = 0.f, t2 = 0.f, t3 = 0.f;
#pragma unroll
            for (int l = 0; l < 64; l += 4) {
                t0 += col[l];     t1 += col[l + 1];
                t2 += col[l + 2]; t3 += col[l + 3];
            }
            Traw[hh][m] = (t0 + t1) + (t2 + t3);
        }
    }
    __syncthreads();

    // ---------- P3: factorial-scaled tables (j+i <= 8) ----------
    if (tid < NH * 45) {
        const int hh = tid / 45;
        int mm = tid % 45, s = 0;
        while (mm > s) { mm -= s + 1; ++s; }
        const int j = mm, i = s - mm;
        float fj = 1.0f, fi = 1.0f;
        for (int t = 2; t <= j; ++t) fj *= (float)t;
        for (int t = 2; t <= i; ++t) fi *= (float)t;
        const float invf = 1.0f / (fj * fi);
        const int id0 = s * (s + 1) / 2 + j;
        const int ida = (s + 1) * (s + 2) / 2 + (j + 1);
        const int idb = (s + 1) * (s + 2) / 2 + j;
        Ts[hh][j][i] = Traw[hh][id0] * invf;
        Ta[hh][j][i] = Traw[hh][ida] * invf;
        Tb[hh][j][i] = Traw[hh][idb] * invf;
    }
    __syncthreads();

    // ---------- P4: q-side dots; thread = (q, head) ----------
    {
        const int q  = tid >> 2;
        const int hh = tid & 3;
        const float CF = 0.70710678118654752f;  // 1/sqrt(head_dim)
        const float qfu = Qf[q][2 * hh] * CF;
        const float qfv = Qf[q][2 * hh + 1] * CF;
        float pu[9], pv[9];
        pu[0] = 1.0f; pv[0] = 1.0f;
#pragma unroll
        for (int j = 1; j <= 8; ++j) { pu[j] = pu[j - 1] * qfu; pv[j] = pv[j - 1] * qfv; }
        float d = 0.0f, a0 = 0.0f, a1 = 0.0f;
#pragma unroll
        for (int s = 0; s <= 8; ++s)
#pragma unroll
            for (int j = 0; j <= s; ++j) {
                const float base = pu[j] * pv[s - j];
                d  = __builtin_fmaf(base, Ts[hh][j][s - j], d);
                a0 = __builtin_fmaf(base, Ta[hh][j][s - j], a0);
                a1 = __builtin_fmaf(base, Tb[hh][j][s - j], a1);
            }
        const float inv = 1.0f / d;
        O[q][2 * hh]     = a0 * inv;
        O[q][2 * hh + 1] = a1 * inv;
    }
    __syncthreads();

    // ---------- P5: projection out = O @ W^T (2 adjacent e per thread) ----------
    {
        const int q  = tid >> 2;
        const int ep = tid & 3;
        float s0 = 0.0f, s1 = 0.0f;
#pragma unroll
        for (int f = 0; f < NW; ++f) {
            s0 = __builtin_fmaf(O[q][f], W[(2 * ep) * NW + f], s0);
            s1 = __builtin_fmaf(O[q][f], W[(2 * ep + 1) * NW + f], s1);
        }
        float* op = out + ((size_t)(b * SS + qc * QB + q)) * NW + 2 * ep;
        *reinterpret_cast<float2*>(op) = make_float2(s0, s1);
    }
}

extern "C" void kernel_launch(void* const* d_in, const int* in_sizes, int n_in,
                              void* d_out, int out_size, void* d_ws, size_t ws_size,
                              hipStream_t stream) {
    const float* x     = (const float*)d_in[0];
    const int*   mask  = (const int*)d_in[1];
    const float* theta = (const float*)d_in[2];
    const float* wout  = (const float*)d_in[3];
    float* out = (float*)d_out;

    mhaq_one<<<dim3(BB * (SS / QB)), dim3(256), 0, stream>>>(x, mask, theta, wout, out);
}

// Round 10
// 15.369 us; speedup vs baseline: 1.0377x; 1.0377x over previous
//
#include <hip/hip_runtime.h>

// Problem constants (fixed by setup_inputs)
#define BB 16
#define SS 1024
#define NW 8
#define QB 64
#define NH 4

// Raw moments T[j][i] = sum_k (mf*u)^j (mf*v)^i over keys, j+i <= 9 (55, triangle
// index m = s(s+1)/2 + j with s=j+i). Weights use Taylor(exp, deg 8): j+i<=8.
__global__ __launch_bounds__(256)
void mhaq_one(const float* __restrict__ x, const int* __restrict__ mask,
              const float* __restrict__ theta, const float* __restrict__ wout,
              float* __restrict__ out)
{
    __shared__ float2 P[NH][SS];     // (u*mf, v*mf) per head/key: 32 KB
    __shared__ float  Qf[QB][NW];    // unmasked q features (this chunk)
    __shared__ float  O[QB][NW];     // attention outputs pre-projection
    __shared__ float  W[64];
    __shared__ float  Traw[NH][55];
    __shared__ float  Ts[NH][9][12], Ta[NH][9][12], Tb[NH][9][12];
    __shared__ int    CMcnt;         // masked-key count

    const int tid = threadIdx.x;
    const int b   = blockIdx.x >> 4;
    const int qc  = blockIdx.x & 15;

    if (tid == 0) CMcnt = 0;

    float th[NW];
#pragma unroll
    for (int e = 0; e < NW; ++e) th[e] = theta[e];

    // ---------- P1: features for all 1024 rows of batch b (4 rows/thread) ----------
    int localMasked = 0;
#pragma unroll
    for (int c = 0; c < 4; ++c) {
        const int row = tid + 256 * c;
        const float* xr = x + ((size_t)b * SS + row) * NW;
        const float4 r0 = *reinterpret_cast<const float4*>(xr);
        const float4 r1 = *reinterpret_cast<const float4*>(xr + 4);
        float g[NW];
        g[0] = __cosf(r0.x + th[0]); g[1] = __cosf(r0.y + th[1]);
        g[2] = __cosf(r0.z + th[2]); g[3] = __cosf(r0.w + th[3]);
        g[4] = __cosf(r1.x + th[4]); g[5] = __cosf(r1.y + th[5]);
        g[6] = __cosf(r1.z + th[6]); g[7] = __cosf(r1.w + th[7]);
        float h[NW];
        h[1] = g[0] * g[1]; h[2] = h[1] * g[2]; h[3] = h[2] * g[3];
        h[4] = h[3] * g[4]; h[5] = h[4] * g[5]; h[6] = h[5] * g[6];
        h[7] = h[6] * g[7];
        h[0] = (g[1] * g[2]) * (g[3] * g[4]) * ((g[5] * g[6]) * g[7]);
        const float mf = (mask[b * SS + row] != 0) ? 1.0f : 0.0f;
        localMasked += (mf == 0.0f) ? 1 : 0;
#pragma unroll
        for (int hd = 0; hd < NH; ++hd)
            P[hd][row] = make_float2(h[2 * hd] * mf, h[2 * hd + 1] * mf);
        const int r = row - qc * QB;
        if ((unsigned)r < (unsigned)QB) {
            *reinterpret_cast<float4*>(&Qf[r][0]) = make_float4(h[0], h[1], h[2], h[3]);
            *reinterpret_cast<float4*>(&Qf[r][4]) = make_float4(h[4], h[5], h[6], h[7]);
        }
    }
    if (localMasked) atomicAdd(&CMcnt, localMasked);
    if (tid < 64) W[tid] = wout[tid];
    __syncthreads();

    // ---------- P2: full moment table; wave = head, lane = key slice ----------
    {
        const int hd = tid >> 6, lane = tid & 63;
        float acc[55];
#pragma unroll
        for (int m = 1; m < 55; ++m) acc[m] = 0.0f;
#pragma unroll 4
        for (int c = 0; c < 16; ++c) {
            const float2 uv = P[hd][c * 64 + lane];
            float muj[10], mvi[10];
            muj[0] = 1.0f; muj[1] = uv.x;
            mvi[0] = 1.0f; mvi[1] = uv.y;
#pragma unroll
            for (int j = 2; j <= 9; ++j) { muj[j] = muj[j - 1] * uv.x; mvi[j] = mvi[j - 1] * uv.y; }
#pragma unroll
            for (int s = 1; s <= 9; ++s)
#pragma unroll
                for (int j = 0; j <= s; ++j)
                    acc[s * (s + 1) / 2 + j] =
                        __builtin_fmaf(muj[j], mvi[s - j], acc[s * (s + 1) / 2 + j]);
        }
#pragma unroll
        for (int st = 1; st <= 32; st <<= 1)
#pragma unroll
            for (int m = 1; m < 55; ++m) acc[m] += __shfl_xor(acc[m], st);
        if (lane == 0) {
            Traw[hd][0] = (float)(SS - CMcnt);  // moment (0,0) = unmasked count
#pragma unroll
            for (int m = 1; m < 55; ++m) Traw[hd][m] = acc[m];
        }
    }
    __syncthreads();

    // ---------- P3: factorial-scaled tables (j+i <= 8) ----------
    if (tid < NH * 45) {
        const int hh = tid / 45;
        int mm = tid % 45, s = 0;
        while (mm > s) { mm -= s + 1; ++s; }
        const int j = mm, i = s - mm;
        float fj = 1.0f, fi = 1.0f;
        for (int t = 2; t <= j; ++t) fj *= (float)t;
        for (int t = 2; t <= i; ++t) fi *= (float)t;
        const float invf = 1.0f / (fj * fi);
        const int id0 = s * (s + 1) / 2 + j;
        const int ida = (s + 1) * (s + 2) / 2 + (j + 1);
        const int idb = (s + 1) * (s + 2) / 2 + j;
        Ts[hh][j][i] = Traw[hh][id0] * invf;
        Ta[hh][j][i] = Traw[hh][ida] * invf;
        Tb[hh][j][i] = Traw[hh][idb] * invf;
    }
    __syncthreads();

    // ---------- P4: q-side dots; thread = (q, head) ----------
    {
        const int q  = tid >> 2;
        const int hh = tid & 3;
        const float CF = 0.70710678118654752f;  // 1/sqrt(head_dim)
        const float qfu = Qf[q][2 * hh] * CF;
        const float qfv = Qf[q][2 * hh + 1] * CF;
        float pu[9], pv[9];
        pu[0] = 1.0f; pv[0] = 1.0f;
#pragma unroll
        for (int j = 1; j <= 8; ++j) { pu[j] = pu[j - 1] * qfu; pv[j] = pv[j - 1] * qfv; }
        float d = 0.0f, a0 = 0.0f, a1 = 0.0f;
#pragma unroll
        for (int s = 0; s <= 8; ++s)
#pragma unroll
            for (int j = 0; j <= s; ++j) {
                const float base = pu[j] * pv[s - j];
                d  = __builtin_fmaf(base, Ts[hh][j][s - j], d);
                a0 = __builtin_fmaf(base, Ta[hh][j][s - j], a0);
                a1 = __builtin_fmaf(base, Tb[hh][j][s - j], a1);
            }
        const float inv = 1.0f / d;
        O[q][2 * hh]     = a0 * inv;
        O[q][2 * hh + 1] = a1 * inv;
    }
    __syncthreads();

    // ---------- P5: projection out = O @ W^T (2 adjacent e per thread) ----------
    {
        const int q  = tid >> 2;
        const int ep = tid & 3;
        float s0 = 0.0f, s1 = 0.0f;
#pragma unroll
        for (int f = 0; f < NW; ++f) {
            s0 = __builtin_fmaf(O[q][f], W[(2 * ep) * NW + f], s0);
            s1 = __builtin_fmaf(O[q][f], W[(2 * ep + 1) * NW + f], s1);
        }
        float* op = out + ((size_t)(b * SS + qc * QB + q)) * NW + 2 * ep;
        *reinterpret_cast<float2*>(op) = make_float2(s0, s1);
    }
}

extern "C" void kernel_launch(void* const* d_in, const int* in_sizes, int n_in,
                              void* d_out, int out_size, void* d_ws, size_t ws_size,
                              hipStream_t stream) {
    const float* x     = (const float*)d_in[0];
    const int*   mask  = (const int*)d_in[1];
    const float* theta = (const float*)d_in[2];
    const float* wout  = (const float*)d_in[3];
    float* out = (float*)d_out;

    mhaq_one<<<dim3(BB * (SS / QB)), dim3(256), 0, stream>>>(x, mask, theta, wout, out);
}